// Round 9
// baseline (293.972 us; speedup 1.0000x reference)
//
#include <hip/hip_runtime.h>
#include <hip/hip_bf16.h>
#include <cstddef>

// X=4096, H=1024, L=8, VT=512, ET=1024
// z = [input_x(4096) ; h_prev[l](1024) ; prev_layer(1024)] -> 6144 cols
// Wg: (L, 4H, 6144) row-major fp32. Gate order: i, f, o, s.
// Head: out[r] = sum_l Wh[r, l*H:(l+1)*H] . hidden[l] + bias  (Wh = Wy|We)

#define XDIM 4096
#define HDIM 1024
#define LNUM 8
#define ZDIM 6144
#define ZPAR 5120   // X + H (scan-independent prefix)
#define VT 512
#define ET 1024
#define NR (VT + ET)        // 1536 head rows
#define NCNT 16             // split completion counters
#define GRP (1024 / NCNT)   // signals per counter = 64

typedef float f4 __attribute__((ext_vector_type(4)));

__device__ __forceinline__ float sigmoidf_(float v) {
    return 1.0f / (1.0f + expf(-v));
}
__device__ __forceinline__ float dot4_(float4 a, float4 b) {
    return a.x * b.x + a.y * b.y + a.z * b.z + a.w * b.w;
}
__device__ __forceinline__ float dotv_(f4 a, f4 b) {
    return a.x * b.x + a.y * b.y + a.z * b.z + a.w * b.w;
}
// Coherent (LLC) poll load: bypasses L1/L2, NO cache-invalidate side effects.
__device__ __forceinline__ int load_i32_cohere(const int* p) {
    int v;
    asm volatile("global_load_dword %0, %1, off sc0 sc1\n\t"
                 "s_waitcnt vmcnt(0)"
                 : "=v"(v) : "v"(p) : "memory");
    return v;
}

// ---------------------------------------------------------------------------
// Kernel P: prefix dots for ALL rows (cols 0:5120) + fused layer-0 LSTM cell.
// Exact R7 geometry (proven 169 µs config). Block 0 zeroes sync counters.
// ---------------------------------------------------------------------------
__global__ __launch_bounds__(256, 4) void prefix_kernel(
    const float* __restrict__ x,
    const float* __restrict__ hprev,
    const float* __restrict__ Wg,
    const float* __restrict__ bg,
    const float* __restrict__ old_state,
    float* __restrict__ partial,
    float* __restrict__ hidden,
    int* __restrict__ cnt)
{
    __shared__ float z[ZPAR];      // 20 KB
    __shared__ float g2[4][2];

    const int tid  = threadIdx.x;
    const int wave = tid >> 6;
    const int lane = tid & 63;
    const int l    = blockIdx.x >> 9;
    const int h0   = (blockIdx.x & 511) * 2;

    if (blockIdx.x == 0 && tid < LNUM * NCNT)
        cnt[tid] = 0;

    for (int i = tid; i < XDIM / 4; i += 256)
        reinterpret_cast<float4*>(z)[i] = reinterpret_cast<const float4*>(x)[i];
    reinterpret_cast<float4*>(z + XDIM)[tid] =
        reinterpret_cast<const float4*>(hprev + (size_t)l * HDIM)[tid];
    __syncthreads();

    const size_t rA = (size_t)l * 4096 + (size_t)wave * HDIM + h0;
    const size_t rB = rA + 1;
    const float4* __restrict__ WA = reinterpret_cast<const float4*>(Wg + rA * ZDIM);
    const float4* __restrict__ WB = reinterpret_cast<const float4*>(Wg + rB * ZDIM);
    const float4* __restrict__ z4 = reinterpret_cast<const float4*>(z);

    float accA = 0.0f, accB = 0.0f;
    #pragma unroll 4
    for (int p = 0; p < 20; ++p) {              // 1280 float4 / 64 lanes
        const int idx = p * 64 + lane;
        float4 wa = WA[idx];
        float4 wb = WB[idx];
        float4 v  = z4[idx];
        accA += dot4_(wa, v);
        accB += dot4_(wb, v);
    }
    #pragma unroll
    for (int off = 32; off > 0; off >>= 1) {
        accA += __shfl_down(accA, off, 64);
        accB += __shfl_down(accB, off, 64);
    }

    if (l > 0) {
        if (lane == 0) {
            partial[rA] = accA + bg[rA];
            partial[rB] = accB + bg[rB];
        }
    } else {
        if (lane == 0) {
            g2[wave][0] = accA + bg[rA];
            g2[wave][1] = accB + bg[rB];
        }
        __syncthreads();
        if (tid == 0) {
            #pragma unroll
            for (int k = 0; k < 2; ++k) {
                const float ig = sigmoidf_(g2[0][k]);
                const float fg = sigmoidf_(g2[1][k]);
                const float og = sigmoidf_(g2[2][k]);
                const float sg = tanhf(g2[3][k]);
                const float ns = fg * old_state[h0 + k] + ig * sg;
                hidden[h0 + k] = og * tanhf(ns);
            }
        }
    }
}

// ---------------------------------------------------------------------------
// Kernel C: fused carry chain (layers 1..7) + distributed head + finish.
// 1024 blocks x 256, __launch_bounds__(256,4) -> all blocks co-resident.
// Sync per layer: write-through store (sc0 sc1) + per-wave vmcnt(0) +
// RELAXED agent atomicAdd into 16 split counters; consumers poll with
// explicit sc0 sc1 loads. ZERO cache-maintenance instructions (the R3/R5
// disaster was acquire/release emitting buffer_inv / buffer_wbl2).
// Next-layer W carry slice + head slice are register-prefetched BEFORE the
// wait; wave 0 prefetches AFTER the signal so the signal's vmcnt(0) never
// waits on streaming loads (vmcnt is per-wave).
// ---------------------------------------------------------------------------
__global__ __launch_bounds__(256, 4) void carry_all_kernel(
    const float* __restrict__ Wg,
    const float* __restrict__ partial,
    const float* __restrict__ old_state,
    const float* __restrict__ Wy, const float* __restrict__ by,
    const float* __restrict__ We, const float* __restrict__ be,
    float* __restrict__ hidden,
    int* __restrict__ cnt,
    float* __restrict__ out)
{
    __shared__ float gred[4];
    __shared__ float hred[2][4];

    const int tid  = threadIdx.x;
    const int wave = tid >> 6;
    const int lane = tid & 63;
    const int h    = blockIdx.x;
    const bool do_head = (h < NR / 2);

    const int r0 = 2 * h, r1 = 2 * h + 1;
    const f4* HW0 = nullptr;
    const f4* HW1 = nullptr;
    float bias0 = 0.0f, bias1 = 0.0f;
    if (do_head) {
        const float* p0 = (r0 < VT) ? (Wy + (size_t)r0 * (LNUM * HDIM))
                                    : (We + (size_t)(r0 - VT) * (LNUM * HDIM));
        const float* p1 = (r1 < VT) ? (Wy + (size_t)r1 * (LNUM * HDIM))
                                    : (We + (size_t)(r1 - VT) * (LNUM * HDIM));
        HW0 = (const f4*)p0;
        HW1 = (const f4*)p1;
        if (tid == 64)  bias0 = (r0 < VT) ? by[r0] : be[r0 - VT];
        if (tid == 128) bias1 = (r1 < VT) ? by[r1] : be[r1 - VT];
    }

    // initial prefetch: layer-1 W carry slice, partial, head chunk 0, old_state
    size_t row = (size_t)4096 + (size_t)wave * HDIM + h;
    const f4* W4 = (const f4*)(Wg + row * ZDIM + ZPAR);
    f4 w0 = W4[lane], w1 = W4[64 + lane], w2 = W4[128 + lane], w3 = W4[192 + lane];
    float part = partial[row];
    f4 a0 = (f4)0.0f, a1 = (f4)0.0f;
    if (do_head) {
        const int ix = wave * 64 + lane;   // chunk 0
        a0 = HW0[ix];
        a1 = HW1[ix];
    }
    float os = (tid == 0) ? old_state[HDIM + h] : 0.0f;
    float hacc0 = 0.0f, hacc1 = 0.0f;      // live in tid 64 / tid 128

    for (int l = 1; l < LNUM; ++l) {
        if (l >= 2) {
            if (tid < NCNT) {
                const int* cp = &cnt[(l - 1) * NCNT + tid];
                while (load_i32_cohere(cp) < GRP)
                    __builtin_amdgcn_s_sleep(2);
            }
        }
        __syncthreads();

        // coherent read of hidden[l-1] slice (bypass stale caches)
        f4 v0, v1, v2, v3;
        {
            const float* hp = hidden + (size_t)(l - 1) * HDIM + lane * 4;
            asm volatile(
                "global_load_dwordx4 %0, %4, off sc0 sc1\n\t"
                "global_load_dwordx4 %1, %4, off offset:1024 sc0 sc1\n\t"
                "global_load_dwordx4 %2, %4, off offset:2048 sc0 sc1\n\t"
                "global_load_dwordx4 %3, %4, off offset:3072 sc0 sc1\n\t"
                "s_waitcnt vmcnt(0)"
                : "=v"(v0), "=v"(v1), "=v"(v2), "=v"(v3)
                : "v"(hp) : "memory");
        }

        float acc = dotv_(w0, v0) + dotv_(w1, v1) + dotv_(w2, v2) + dotv_(w3, v3);
        float d0 = 0.0f, d1 = 0.0f;
        if (do_head) {
            f4 hv = (wave == 0) ? v0 : (wave == 1) ? v1 : (wave == 2) ? v2 : v3;
            d0 = dotv_(a0, hv);
            d1 = dotv_(a1, hv);
        }

        // prefetch next layer (waves 1-3 now; wave 0 after the signal)
        float part_next = 0.0f, os_next = 0.0f;
        if (wave != 0) {
            if (l < LNUM - 1) {
                const size_t nrow = row + 4096;
                const f4* NW = (const f4*)(Wg + nrow * ZDIM + ZPAR);
                w0 = NW[lane]; w1 = NW[64 + lane];
                w2 = NW[128 + lane]; w3 = NW[192 + lane];
                part_next = partial[nrow];
            }
            if (do_head) {
                const int ix = l * 256 + wave * 64 + lane;   // chunk l
                a0 = HW0[ix];
                a1 = HW1[ix];
            }
        }

        #pragma unroll
        for (int off = 32; off > 0; off >>= 1)
            acc += __shfl_down(acc, off, 64);
        if (lane == 0)
            gred[wave] = acc + part;
        if (do_head) {
            #pragma unroll
            for (int off = 32; off > 0; off >>= 1) {
                d0 += __shfl_down(d0, off, 64);
                d1 += __shfl_down(d1, off, 64);
            }
            if (lane == 0) { hred[0][wave] = d0; hred[1][wave] = d1; }
        }
        __syncthreads();

        if (tid == 0) {
            const float ig = sigmoidf_(gred[0]);
            const float fg = sigmoidf_(gred[1]);
            const float og = sigmoidf_(gred[2]);
            const float sg = tanhf(gred[3]);
            const float ns = fg * os + ig * sg;
            const float val = og * tanhf(ns);
            float* dst = hidden + (size_t)l * HDIM + h;
            // write-through store; per-wave vmcnt(0) (only this store pending)
            asm volatile("global_store_dword %0, %1, off sc0 sc1\n\t"
                         "s_waitcnt vmcnt(0)"
                         :: "v"(dst), "v"(val) : "memory");
            // relaxed agent signal: NO fence instructions emitted
            __hip_atomic_fetch_add(&cnt[l * NCNT + (h & (NCNT - 1))], 1,
                                   __ATOMIC_RELAXED, __HIP_MEMORY_SCOPE_AGENT);
        }
        if (do_head) {
            if (tid == 64)
                hacc0 += hred[0][0] + hred[0][1] + hred[0][2] + hred[0][3];
            if (tid == 128)
                hacc1 += hred[1][0] + hred[1][1] + hred[1][2] + hred[1][3];
        }

        // wave 0 prefetch (after signal; its loads no longer gate vmcnt(0))
        if (wave == 0) {
            if (l < LNUM - 1) {
                const size_t nrow = row + 4096;
                const f4* NW = (const f4*)(Wg + nrow * ZDIM + ZPAR);
                w0 = NW[lane]; w1 = NW[64 + lane];
                w2 = NW[128 + lane]; w3 = NW[192 + lane];
                part_next = partial[nrow];
                if (tid == 0) os_next = old_state[(size_t)(l + 1) * HDIM + h];
            }
            if (do_head) {
                const int ix = l * 256 + lane;               // chunk l, wave 0
                a0 = HW0[ix];
                a1 = HW1[ix];
            }
        }
        row += 4096;
        part = part_next;
        if (tid == 0) os = os_next;
    }

    // ---- epilogue: head chunk 7 + bias ----
    if (!do_head) return;
    if (tid < NCNT) {
        const int* cp = &cnt[(LNUM - 1) * NCNT + tid];
        while (load_i32_cohere(cp) < GRP)
            __builtin_amdgcn_s_sleep(2);
    }
    __syncthreads();

    f4 hv;
    {
        const float* hp = hidden + (size_t)(LNUM - 1) * HDIM + (wave * 64 + lane) * 4;
        asm volatile("global_load_dwordx4 %0, %1, off sc0 sc1\n\t"
                     "s_waitcnt vmcnt(0)"
                     : "=v"(hv) : "v"(hp) : "memory");
    }
    float d0 = dotv_(a0, hv);   // a0,a1 hold chunk 7 (loaded at l=7)
    float d1 = dotv_(a1, hv);
    #pragma unroll
    for (int off = 32; off > 0; off >>= 1) {
        d0 += __shfl_down(d0, off, 64);
        d1 += __shfl_down(d1, off, 64);
    }
    if (lane == 0) { hred[0][wave] = d0; hred[1][wave] = d1; }
    __syncthreads();

    if (tid == 64)
        out[r0] = hacc0 + hred[0][0] + hred[0][1] + hred[0][2] + hred[0][3] + bias0;
    if (tid == 128)
        out[r1] = hacc1 + hred[1][0] + hred[1][1] + hred[1][2] + hred[1][3] + bias1;
}

// ---------------------------------------------------------------------------
extern "C" void kernel_launch(void* const* d_in, const int* in_sizes, int n_in,
                              void* d_out, int out_size, void* d_ws, size_t ws_size,
                              hipStream_t stream)
{
    const float* x         = (const float*)d_in[0];
    const float* hprev     = (const float*)d_in[1];
    const float* Wg        = (const float*)d_in[2];
    const float* bg        = (const float*)d_in[3];
    const float* old_state = (const float*)d_in[4];
    const float* Wy        = (const float*)d_in[5];
    const float* by        = (const float*)d_in[6];
    const float* We        = (const float*)d_in[7];
    const float* be        = (const float*)d_in[8];
    float* out = (float*)d_out;

    float* hidden  = (float*)d_ws;                 // L*H floats
    float* partial = hidden + LNUM * HDIM;         // L*4H floats
    int*   cnt     = (int*)(partial + LNUM * 4 * HDIM);  // L*NCNT ints

    // 1) prefix dots for all layers + layer-0 cell + counter zeroing
    prefix_kernel<<<4096, 256, 0, stream>>>(
        x, hprev, Wg, bg, old_state, partial, hidden, cnt);

    // 2) fused carry chain + distributed head + finish (one launch)
    carry_all_kernel<<<1024, 256, 0, stream>>>(
        Wg, partial, old_state, Wy, by, We, be, hidden, cnt, out);
}

// Round 10
// 168.808 us; speedup vs baseline: 1.7415x; 1.7415x over previous
//
#include <hip/hip_runtime.h>
#include <hip/hip_bf16.h>
#include <cstddef>

// X=4096, H=1024, L=8, VT=512, ET=1024
// z = [input_x(4096) ; h_prev[l](1024) ; prev_layer(1024)] -> 6144 cols
// Wg: (L, 4H, 6144) row-major fp32. Gate order: i, f, o, s.
// Head: out[r] = sum_l Wh[r, l*H:(l+1)*H] . hidden[l] + bias  (Wh = Wy|We)

#define XDIM 4096
#define HDIM 1024
#define LNUM 8
#define ZDIM 6144
#define ZPAR 5120   // X + H (scan-independent prefix)
#define VT 512
#define ET 1024
#define NR (VT + ET)   // 1536 head rows

__device__ __forceinline__ float sigmoidf_(float v) {
    return 1.0f / (1.0f + expf(-v));
}
__device__ __forceinline__ float dot4_(float4 a, float4 b) {
    return a.x * b.x + a.y * b.y + a.z * b.z + a.w * b.w;
}

// ---------------------------------------------------------------------------
// Kernel P: prefix dots for ALL rows (cols 0:5120) + fused layer-0 LSTM cell.
// grid = 4096 blocks (8 layers x 512) x 256. Block b: l=b>>9, h0=(b&511)*2.
// Wave w computes rows rA=l*4096+w*1024+h0, rB=rA+1 (shared LDS z reads).
// ---------------------------------------------------------------------------
__global__ __launch_bounds__(256, 4) void prefix_kernel(
    const float* __restrict__ x,
    const float* __restrict__ hprev,
    const float* __restrict__ Wg,
    const float* __restrict__ bg,
    const float* __restrict__ old_state,
    float* __restrict__ partial,
    float* __restrict__ hidden)
{
    __shared__ float z[ZPAR];      // 20 KB
    __shared__ float g2[4][2];

    const int tid  = threadIdx.x;
    const int wave = tid >> 6;
    const int lane = tid & 63;
    const int l    = blockIdx.x >> 9;
    const int h0   = (blockIdx.x & 511) * 2;

    for (int i = tid; i < XDIM / 4; i += 256)
        reinterpret_cast<float4*>(z)[i] = reinterpret_cast<const float4*>(x)[i];
    reinterpret_cast<float4*>(z + XDIM)[tid] =
        reinterpret_cast<const float4*>(hprev + (size_t)l * HDIM)[tid];
    __syncthreads();

    const size_t rA = (size_t)l * 4096 + (size_t)wave * HDIM + h0;
    const size_t rB = rA + 1;
    const float4* __restrict__ WA = reinterpret_cast<const float4*>(Wg + rA * ZDIM);
    const float4* __restrict__ WB = reinterpret_cast<const float4*>(Wg + rB * ZDIM);
    const float4* __restrict__ z4 = reinterpret_cast<const float4*>(z);

    float accA = 0.0f, accB = 0.0f;
    #pragma unroll 4
    for (int p = 0; p < 20; ++p) {              // 1280 float4 / 64 lanes
        const int idx = p * 64 + lane;
        float4 wa = WA[idx];
        float4 wb = WB[idx];
        float4 v  = z4[idx];
        accA += dot4_(wa, v);
        accB += dot4_(wb, v);
    }
    #pragma unroll
    for (int off = 32; off > 0; off >>= 1) {
        accA += __shfl_down(accA, off, 64);
        accB += __shfl_down(accB, off, 64);
    }

    if (l > 0) {
        if (lane == 0) {
            partial[rA] = accA + bg[rA];
            partial[rB] = accB + bg[rB];
        }
    } else {
        if (lane == 0) {
            g2[wave][0] = accA + bg[rA];
            g2[wave][1] = accB + bg[rB];
        }
        __syncthreads();
        if (tid == 0) {
            #pragma unroll
            for (int k = 0; k < 2; ++k) {
                const float ig = sigmoidf_(g2[0][k]);
                const float fg = sigmoidf_(g2[1][k]);
                const float og = sigmoidf_(g2[2][k]);
                const float sg = tanhf(g2[3][k]);
                const float ns = fg * old_state[h0 + k] + ig * sg;
                hidden[h0 + k] = og * tanhf(ns);
            }
        }
    }
}

// ---------------------------------------------------------------------------
// Kernel C (per layer l=1..7): carry dot (cols 5120:6144) + cell math,
// PLUS head-chunk (l-1): headacc[r] += Wh[r,(l-1)H:lH] . hidden[l-1].
// grid = 1024 blocks x 256. Block h: wave q = gate q's carry dot.
// hidden[l-1] loaded per-lane direct from global (L2-hot, no LDS staging);
// wave w's carry fragment v_w doubles as its head slice (cols w*256..).
// Blocks 0..767 also handle head rows r0=2b, r1=2b+1 (2 extra loads/lane).
// l==1 WRITES headacc (ws is poisoned 0xAA, never accumulate into poison).
// ---------------------------------------------------------------------------
__global__ __launch_bounds__(256) void carry_kernel(
    const float* __restrict__ Wg,
    const float* __restrict__ partial,
    const float* __restrict__ old_state,
    const float* __restrict__ hidden_prev,  // hidden[l-1]
    float* __restrict__ hidden_out,         // hidden[l]
    const float* __restrict__ Wy,
    const float* __restrict__ We,
    float* __restrict__ headacc,            // NR floats
    int l)
{
    __shared__ float gred[4];
    __shared__ float hred[2][4];

    const int tid  = threadIdx.x;
    const int wave = tid >> 6;
    const int lane = tid & 63;
    const int h    = blockIdx.x;
    const bool do_head = (blockIdx.x < NR / 2);

    const size_t row = (size_t)l * 4096 + (size_t)wave * HDIM + h;
    const float4* __restrict__ W4 =
        reinterpret_cast<const float4*>(Wg + row * ZDIM + ZPAR);
    const float4* __restrict__ h4 =
        reinterpret_cast<const float4*>(hidden_prev);

    // issue all independent loads up front
    float4 w0 = W4[lane], w1 = W4[64 + lane], w2 = W4[128 + lane], w3 = W4[192 + lane];
    float4 v0 = h4[lane], v1 = h4[64 + lane], v2 = h4[128 + lane], v3 = h4[192 + lane];

    int r0 = 0, r1 = 0;
    float4 a0, a1;
    if (do_head) {
        r0 = 2 * blockIdx.x;
        r1 = r0 + 1;
        const float* Wr0 = (r0 < VT) ? (Wy + (size_t)r0 * (LNUM * HDIM))
                                     : (We + (size_t)(r0 - VT) * (LNUM * HDIM));
        const float* Wr1 = (r1 < VT) ? (Wy + (size_t)r1 * (LNUM * HDIM))
                                     : (We + (size_t)(r1 - VT) * (LNUM * HDIM));
        const int idx = (l - 1) * 256 + wave * 64 + lane;  // chunk l-1, wave slice
        a0 = reinterpret_cast<const float4*>(Wr0)[idx];
        a1 = reinterpret_cast<const float4*>(Wr1)[idx];
    }

    float acc = dot4_(w0, v0) + dot4_(w1, v1) + dot4_(w2, v2) + dot4_(w3, v3);
    #pragma unroll
    for (int off = 32; off > 0; off >>= 1)
        acc += __shfl_down(acc, off, 64);
    if (lane == 0)
        gred[wave] = acc + partial[row];        // partial already includes bg

    if (do_head) {
        // wave w's head slice of hidden = its carry fragment v_w
        float4 hv = (wave == 0) ? v0 : (wave == 1) ? v1 : (wave == 2) ? v2 : v3;
        float d0 = dot4_(a0, hv);
        float d1 = dot4_(a1, hv);
        #pragma unroll
        for (int off = 32; off > 0; off >>= 1) {
            d0 += __shfl_down(d0, off, 64);
            d1 += __shfl_down(d1, off, 64);
        }
        if (lane == 0) { hred[0][wave] = d0; hred[1][wave] = d1; }
    }
    __syncthreads();

    if (tid == 0) {
        const float ig = sigmoidf_(gred[0]);
        const float fg = sigmoidf_(gred[1]);
        const float og = sigmoidf_(gred[2]);
        const float sg = tanhf(gred[3]);
        const float ns = fg * old_state[(size_t)l * HDIM + h] + ig * sg;
        hidden_out[h] = og * tanhf(ns);
    }
    if (do_head) {
        if (tid == 64) {
            const float s = hred[0][0] + hred[0][1] + hred[0][2] + hred[0][3];
            headacc[r0] = ((l == 1) ? 0.0f : headacc[r0]) + s;
        }
        if (tid == 128) {
            const float s = hred[1][0] + hred[1][1] + hred[1][2] + hred[1][3];
            headacc[r1] = ((l == 1) ? 0.0f : headacc[r1]) + s;
        }
    }
}

// ---------------------------------------------------------------------------
// Kernel F: head finish. out[r] = headacc[r] + Wh[r, 7H:8H].hidden[7] + bias.
// grid = 1536 blocks x 256; wave w dots cols [7H + w*256, ...).
// ---------------------------------------------------------------------------
__global__ __launch_bounds__(256) void head_finish_kernel(
    const float* __restrict__ Wy, const float* __restrict__ by,
    const float* __restrict__ We, const float* __restrict__ be,
    const float* __restrict__ hidden,   // full flat (L*H)
    const float* __restrict__ headacc,
    float* __restrict__ out)
{
    __shared__ float gred[4];

    const int tid  = threadIdx.x;
    const int wave = tid >> 6;
    const int lane = tid & 63;
    const int r    = blockIdx.x;

    const float* W;
    float b;
    if (r < VT) { W = Wy + (size_t)r * (LNUM * HDIM);        b = by[r]; }
    else        { W = We + (size_t)(r - VT) * (LNUM * HDIM); b = be[r - VT]; }

    const int idx = 7 * 256 + wave * 64 + lane;   // chunk 7 float4 index
    float4 w = reinterpret_cast<const float4*>(W)[idx];
    float4 v = reinterpret_cast<const float4*>(hidden)[idx];

    float acc = dot4_(w, v);
    #pragma unroll
    for (int off = 32; off > 0; off >>= 1)
        acc += __shfl_down(acc, off, 64);
    if (lane == 0) gred[wave] = acc;
    __syncthreads();

    if (tid == 0)
        out[r] = headacc[r] + gred[0] + gred[1] + gred[2] + gred[3] + b;
}

// ---------------------------------------------------------------------------
extern "C" void kernel_launch(void* const* d_in, const int* in_sizes, int n_in,
                              void* d_out, int out_size, void* d_ws, size_t ws_size,
                              hipStream_t stream)
{
    const float* x         = (const float*)d_in[0];
    const float* hprev     = (const float*)d_in[1];
    const float* Wg        = (const float*)d_in[2];
    const float* bg        = (const float*)d_in[3];
    const float* old_state = (const float*)d_in[4];
    const float* Wy        = (const float*)d_in[5];
    const float* by        = (const float*)d_in[6];
    const float* We        = (const float*)d_in[7];
    const float* be        = (const float*)d_in[8];
    float* out = (float*)d_out;

    float* hidden  = (float*)d_ws;                 // L*H floats
    float* partial = hidden + LNUM * HDIM;         // L*4H floats
    float* headacc = partial + LNUM * 4 * HDIM;    // NR floats

    // 1) prefix dots for all layers + layer-0 cell
    prefix_kernel<<<4096, 256, 0, stream>>>(
        x, hprev, Wg, bg, old_state, partial, hidden);

    // 2) sequential carry chain (layers 1..7), head chunks 0..6 ride along
    for (int l = 1; l < LNUM; ++l) {
        carry_kernel<<<1024, 256, 0, stream>>>(
            Wg, partial, old_state,
            hidden + (size_t)(l - 1) * HDIM,
            hidden + (size_t)l * HDIM,
            Wy, We, headacc, l);
    }

    // 3) head finish: chunk 7 + bias
    head_finish_kernel<<<NR, 256, 0, stream>>>(
        Wy, by, We, be, hidden, headacc, out);
}